// Round 11
// baseline (3672.115 us; speedup 1.0000x reference)
//
#include <hip/hip_runtime.h>
#include <hip/hip_bf16.h>

#define LSEQ 384
#define BATCH 32
#define BIGV 1e30f
#define TB_STK 448
#define NN ((size_t)LSEQ * LSEQ)

// mask mode: 0 = int32 words, 1 = u8 bytes, 2 = 16-bit halves.
// Wave-parallel detect over bytes 0..63 of seq-0 row 0 (upper triangle,
// never overwritten by choice stores). All lanes return the same value.
__device__ __forceinline__ int detect_mmode_wave(const unsigned char* m0, int lane) {
    unsigned char v = m0[lane & 63];
    unsigned long long big = __ballot(v >= 2);                       // 16-bit 1.0 encodings
    unsigned long long off = __ballot((((lane & 63) & 3) != 0) && (v != 0)); // u8 bools
    return big ? 2 : (off ? 1 : 0);
}

__device__ __forceinline__ bool mask_read(const void* mask, size_t idx, int mmode) {
    if (mmode == 0) return ((const unsigned int*)mask)[idx] != 0;
    if (mmode == 1) return ((const unsigned char*)mask)[idx] != 0;
    return ((const unsigned short*)mask)[idx] != 0;
}

__device__ __forceinline__ void choice_write(void* mask, size_t idx, int c, int mmode) {
    if (mmode == 0) ((unsigned int*)mask)[idx] = (unsigned int)c;
    else if (mmode == 1) ((unsigned char*)mask)[idx] = (unsigned char)c;
    else ((unsigned short*)mask)[idx] = (unsigned short)c;
}

__device__ __forceinline__ int choice_read(const void* mask, size_t idx, int mmode) {
    if (mmode == 0) return (int)((const unsigned int*)mask)[idx];
    if (mmode == 1) return (int)((const unsigned char*)mask)[idx];
    return (int)((const unsigned short*)mask)[idx];
}

// DP: one block (1024 threads) per sequence. dp stored IN-PLACE over e_pair:
// dp[i][j] at ep[i*L+j] (upper) and mirrored at ep[j*L+i], so both bif
// streams are contiguous in t. Each cell is computed by P = 2..64 lanes with
// a STRIDE-INTERLEAVED t-split (lane sub handles t = sub + m*P), so the P
// lanes of a cell-group issue consecutive addresses -> coalesced wave loads
// (round-10's chunked split was 64-scattered-lines per load = the 3.4 ms).
// fminf is order-free; value-only; sub==0 resolves the choice by
// equality-priority (== reference first-occurrence argmin).
__global__ __launch_bounds__(1024) void dp_kernel(
    float* __restrict__ e_pair, const float* __restrict__ e_unp,
    void* mask)
{
    const int b = blockIdx.x;
    const int tid = threadIdx.x;
    float* dp = e_pair + (size_t)b * NN;

    __shared__ float s_eunp[LSEQ];
    __shared__ int s_mmode;
    if (tid < 64) {
        int mm = detect_mmode_wave((const unsigned char*)mask, tid);
        if (tid == 0) s_mmode = mm;
    }
    for (int i = tid; i < LSEQ; i += 1024) {
        float v = e_unp[b * LSEQ + i];
        s_eunp[i] = v;
        dp[(size_t)i * LSEQ + i] = v;          // d = 0: dp[i][i] = e_unp[i]
    }
    __syncthreads();
    const int mmode = s_mmode;
    const size_t mb = (size_t)b * NN;

    for (int d = 1; d < LSEQ; ++d) {
        const int cells = LSEQ - d;
        int P = 1024 / cells; if (P > 64) P = 64;
        P = 1 << (31 - __clz(P));              // pow2 in [2,64] for cells<=512
        const int lp = 31 - __clz(P);
        const int cell = tid >> lp;
        const int sub = tid & (P - 1);

        if (cell < cells) {
            const int i = cell;
            const int j = i + d;
            const float* rowi = dp + (size_t)i * LSEQ;   // dp[i][*]
            const float* rowj = dp + (size_t)j * LSEQ;   // mirror: dp[*][j]

            // bif: min_t dp[i][i+t] + dp[i+t+1][j], stride-interleaved split
            const int P2 = P << 1, P3 = P * 3, P4 = P << 2;
            float a0 = BIGV, a1 = BIGV, a2 = BIGV, a3 = BIGV;
            int t = sub;
            for (; t + P3 < d; t += P4) {
                a0 = fminf(a0, rowi[i + t     ] + rowj[i + t + 1     ]);
                a1 = fminf(a1, rowi[i + t + P ] + rowj[i + t + P + 1 ]);
                a2 = fminf(a2, rowi[i + t + P2] + rowj[i + t + P2 + 1]);
                a3 = fminf(a3, rowi[i + t + P3] + rowj[i + t + P3 + 1]);
            }
            for (; t < d; t += P)
                a0 = fminf(a0, rowi[i + t] + rowj[i + t + 1]);
            float acc = fminf(fminf(a0, a1), fminf(a2, a3));
            for (int m = P >> 1; m > 0; m >>= 1)
                acc = fminf(acc, __shfl_xor(acc, m, 64));   // P-group aligned in-wave

            if (sub == 0) {
                float opt0 = rowj[i + 1] + s_eunp[i];       // dp[i+1][j] + e_unp[i]
                float opt1 = rowi[j - 1] + s_eunp[j];       // dp[i][j-1] + e_unp[j]
                float opt2 = BIGV;
                bool allowed = false;
                if (d > 4) {
                    allowed = mask_read(mask, mb + (size_t)i * LSEQ + j, mmode);
                    if (allowed)                            // rowi[j] = ORIGINAL e_pair[i][j]
                        opt2 = dp[(size_t)(i + 1) * LSEQ + (j - 1)] + rowi[j];
                }
                float best = fminf(fminf(opt0, opt1), fminf(opt2, acc));
                // equality-priority == first-occurrence argmin over
                // [opt0, opt1, opt2, bif...] (opt0≡bif(t=0), opt1≡bif(t=d-1);
                // ties resolve to the lower candidate index, as in reference)
                int c;
                if (best == opt0) c = 0;
                else if (best == opt1) c = 1;
                else if (allowed && best == opt2) c = 2;
                else c = 3;
                dp[(size_t)i * LSEQ + j] = best;            // upper
                dp[(size_t)j * LSEQ + i] = best;            // mirror
                choice_write(mask, mb + (size_t)j * LSEQ + i, c, mmode);
            }
        }
        __syncthreads();
    }
}

// Traceback: one 64-lane wave per sequence (32 blocks). All lanes walk the
// stack redundantly (uniform state, broadcast loads); c==3 bif-argmin is a
// 64-wide lexicographic (value, smallest-t) scan + butterfly — identical
// strict-< first-occurrence semantics. Energy = dp[0][L-1].
// OUTPUT: f32, pairs (32,384) then energy (32,).
__global__ __launch_bounds__(64) void tb_kernel(
    const float* __restrict__ e_pair, const void* mask,
    float* __restrict__ out)
{
    const int b = blockIdx.x;
    const int lane = threadIdx.x;
    const float* dp = e_pair + (size_t)b * NN;
    const size_t mb = (size_t)b * NN;
    const int mmode = detect_mmode_wave((const unsigned char*)mask, lane);

    __shared__ short res[LSEQ];
    __shared__ int st[TB_STK];             // packed (i<<16)|j
    for (int l = lane; l < LSEQ; l += 64) res[l] = -1;
    st[0] = (0 << 16) | (LSEQ - 1);        // all lanes, same addr, same value
    __syncthreads();

    int sp = 1;                            // uniform across lanes
    for (int iter = 0; iter < 4096 && sp > 0; ++iter) {
        --sp;
        int pk = st[sp];
        int i = pk >> 16, j = pk & 0xFFFF;
        if (i >= j) continue;
        int c = choice_read(mask, mb + (size_t)j * LSEQ + i, mmode);

        if (c == 0) {
            st[sp] = ((i + 1) << 16) | j; ++sp;
        } else if (c == 1) {
            st[sp] = (i << 16) | (j - 1); ++sp;
        } else if (c == 2) {
            res[i] = (short)j; res[j] = (short)i;
            if (i + 1 <= j - 1) { st[sp] = ((i + 1) << 16) | (j - 1); ++sp; }
        } else {
            const int d = j - i;
            const float* rowi = dp + (size_t)i * LSEQ;
            const float* rowj = dp + (size_t)j * LSEQ;
            float bv = BIGV; int bt = d;   // sentinel t for lex-min
            for (int t = lane; t < d; t += 64) {
                float cc = rowi[i + t] + rowj[i + t + 1];
                if (cc < bv || (cc == bv && t < bt)) { bv = cc; bt = t; }
            }
            for (int m = 32; m > 0; m >>= 1) {
                float ov = __shfl_xor(bv, m, 64);
                int   ot = __shfl_xor(bt, m, 64);
                if (ov < bv || (ov == bv && ot < bt)) { bv = ov; bt = ot; }
            }
            int k = i + bt;
            if (sp < TB_STK - 2) {
                st[sp] = (i << 16) | k; ++sp;            // (i,k) below
                st[sp] = ((k + 1) << 16) | j; ++sp;      // (k+1,j) popped first
            }
        }
        __syncthreads();                   // order LDS writes before next pop
    }

    for (int l = lane; l < LSEQ; l += 64)
        out[b * LSEQ + l] = (float)res[l];               // pairs FIRST, f32
    if (lane == 0)
        out[BATCH * LSEQ + b] = dp[LSEQ - 1];            // energy = dp[0][L-1]
}

extern "C" void kernel_launch(void* const* d_in, const int* in_sizes, int n_in,
                              void* d_out, int out_size, void* d_ws, size_t ws_size,
                              hipStream_t stream) {
    float* e_pair = (float*)d_in[0];        // consumed & overwritten in-place by dp
    const float* e_unp = (const float*)d_in[1];
    void* mask = d_in[2];                   // upper tri read; lower tri = choice store
    (void)d_ws; (void)ws_size;              // zero workspace

    dp_kernel<<<BATCH, 1024, 0, stream>>>(e_pair, e_unp, mask);
    tb_kernel<<<BATCH, 64, 0, stream>>>(e_pair, mask, (float*)d_out);
}

// Round 12
// 1993.958 us; speedup vs baseline: 1.8416x; 1.8416x over previous
//
#include <hip/hip_runtime.h>
#include <hip/hip_bf16.h>

#define LSEQ 384
#define BATCH 32
#define BIGV 1e30f
#define TB_STK 448
#define NN ((size_t)LSEQ * LSEQ)

// mask mode: 0 = int32 words, 1 = u8 bytes, 2 = 16-bit halves.
// Wave-parallel detect over bytes 0..63 of seq-0 row 0 (upper triangle,
// never overwritten by choice stores). All lanes return the same value.
__device__ __forceinline__ int detect_mmode_wave(const unsigned char* m0, int lane) {
    unsigned char v = m0[lane & 63];
    unsigned long long big = __ballot(v >= 2);                       // 16-bit 1.0 encodings
    unsigned long long off = __ballot((((lane & 63) & 3) != 0) && (v != 0)); // u8 bools
    return big ? 2 : (off ? 1 : 0);
}

__device__ __forceinline__ bool mask_read(const void* mask, size_t idx, int mmode) {
    if (mmode == 0) return ((const unsigned int*)mask)[idx] != 0;
    if (mmode == 1) return ((const unsigned char*)mask)[idx] != 0;
    return ((const unsigned short*)mask)[idx] != 0;
}

__device__ __forceinline__ void choice_write(void* mask, size_t idx, int c, int mmode) {
    if (mmode == 0) ((unsigned int*)mask)[idx] = (unsigned int)c;
    else if (mmode == 1) ((unsigned char*)mask)[idx] = (unsigned char)c;
    else ((unsigned short*)mask)[idx] = (unsigned short)c;
}

__device__ __forceinline__ int choice_read(const void* mask, size_t idx, int mmode) {
    if (mmode == 0) return (int)((const unsigned int*)mask)[idx];
    if (mmode == 1) return (int)((const unsigned char*)mask)[idx];
    return (int)((const unsigned short*)mask)[idx];
}

// DP: one block (1024 threads) per sequence. IN-PLACE storage over e_pair:
//   upper  (i,j): dp[i][j]                      (replaces consumed e_pair[i][j])
//   mirror (j,q): M[j][q] = dp[q+1][j]  -> cell (i,j) writes dp[j][i-1];
//                 init writes dp[j][j-1] = e_unp[j].
// SHIFTED mirror makes bif(t) = rowi[q] + Mj[q] with ONE shared index q=i+t,
// so 4 terms = two aligned float4 loads (round 10/11 showed dp is bound by
// memory-instruction count, not coalescing: 4x fewer loads is the lever).
// Each cell: P=2..64 lanes, stride-P over float4 blocks; head/tail (<=3 each,
// unaligned) scalar on sub==0. fminf is order-free; value-only; sub==0
// resolves choice by equality-priority (== reference first-occurrence argmin).
__global__ __launch_bounds__(1024) void dp_kernel(
    float* __restrict__ e_pair, const float* __restrict__ e_unp,
    void* mask)
{
    const int b = blockIdx.x;
    const int tid = threadIdx.x;
    float* dp = e_pair + (size_t)b * NN;

    __shared__ float s_eunp[LSEQ];
    __shared__ int s_mmode;
    if (tid < 64) {
        int mm = detect_mmode_wave((const unsigned char*)mask, tid);
        if (tid == 0) s_mmode = mm;
    }
    for (int i = tid; i < LSEQ; i += 1024) {
        float v = e_unp[b * LSEQ + i];
        s_eunp[i] = v;
        dp[(size_t)i * LSEQ + i] = v;              // d=0 upper: dp[i][i]
        if (i > 0) dp[(size_t)i * LSEQ + i - 1] = v;  // d=0 mirror: M[i][i-1]
    }
    __syncthreads();
    const int mmode = s_mmode;
    const size_t mb = (size_t)b * NN;

    for (int d = 1; d < LSEQ; ++d) {
        const int cells = LSEQ - d;
        int P = 1024 / cells; if (P > 64) P = 64;
        P = 1 << (31 - __clz(P));                  // pow2 in [2,64]
        const int lp = 31 - __clz(P);
        const int cell = tid >> lp;
        const int sub = tid & (P - 1);

        if (cell < cells) {
            const int i = cell;
            const int j = i + d;
            const float* rowi = dp + (size_t)i * LSEQ;    // dp[i][*]
            const float* mrow = dp + (size_t)j * LSEQ;    // M[j][*] (shifted mirror)
            const float4* ri4 = (const float4*)rowi;      // rows are 16B-aligned
            const float4* mj4 = (const float4*)mrow;

            const int qlo = i, qhi = i + d;               // bif q-range [qlo,qhi)
            const int qa = (qlo + 3) & ~3;                // first aligned q
            const int qb = qhi & ~3;                      // last aligned boundary
            float a0 = BIGV, a1 = BIGV;

            // interior full blocks, two aligned float4 loads per 4 terms
            for (int m = (qa >> 2) + sub; m < (qb >> 2); m += P) {
                float4 av = ri4[m];
                float4 bv = mj4[m];
                a0 = fminf(a0, fminf(av.x + bv.x, av.y + bv.y));
                a1 = fminf(a1, fminf(av.z + bv.z, av.w + bv.w));
            }
            // head [qlo, min(qa,qhi)) and tail [max(qa,qb), qhi), scalar
            if (sub == 0) {
                int h1 = qa < qhi ? qa : qhi;
                for (int q = qlo; q < h1; ++q) a0 = fminf(a0, rowi[q] + mrow[q]);
                int t0 = qb > qa ? qb : qa;
                for (int q = t0; q < qhi; ++q) a1 = fminf(a1, rowi[q] + mrow[q]);
            }
            float acc = fminf(a0, a1);
            for (int m = P >> 1; m > 0; m >>= 1)
                acc = fminf(acc, __shfl_xor(acc, m, 64)); // P-group aligned in-wave

            if (sub == 0) {
                float opt0 = mrow[i] + s_eunp[i];         // dp[i+1][j] = M[j][i]
                float opt1 = rowi[j - 1] + s_eunp[j];     // dp[i][j-1]
                float opt2 = BIGV;
                bool allowed = false;
                if (d > 4) {
                    allowed = mask_read(mask, mb + (size_t)i * LSEQ + j, mmode);
                    if (allowed)                          // rowi[j] = ORIGINAL e_pair[i][j]
                        opt2 = dp[(size_t)(i + 1) * LSEQ + (j - 1)] + rowi[j];
                }
                float best = fminf(fminf(opt0, opt1), fminf(opt2, acc));
                // equality-priority == first-occurrence argmin over
                // [opt0, opt1, opt2, bif...] (opt0==bif(t=0), opt1==bif(t=d-1);
                // ties resolve to the lower candidate index, as in reference)
                int c;
                if (best == opt0) c = 0;
                else if (best == opt1) c = 1;
                else if (allowed && best == opt2) c = 2;
                else c = 3;
                dp[(size_t)i * LSEQ + j] = best;          // upper
                if (i > 0) dp[(size_t)j * LSEQ + i - 1] = best;   // shifted mirror
                choice_write(mask, mb + (size_t)j * LSEQ + i, c, mmode);
            }
        }
        __syncthreads();
    }
}

// Traceback: one 64-lane wave per sequence (32 blocks). All lanes walk the
// stack redundantly (uniform state, broadcast loads); c==3 bif-argmin is a
// 64-wide lexicographic (value, smallest-t) scan + butterfly — identical
// strict-< first-occurrence semantics. Uses the shared-index bif form:
// bif(t) = dp[i][q] + M[j][q], q = i+t. Energy = dp[0][L-1].
// OUTPUT: f32, pairs (32,384) then energy (32,).
__global__ __launch_bounds__(64) void tb_kernel(
    const float* __restrict__ e_pair, const void* mask,
    float* __restrict__ out)
{
    const int b = blockIdx.x;
    const int lane = threadIdx.x;
    const float* dp = e_pair + (size_t)b * NN;
    const size_t mb = (size_t)b * NN;
    const int mmode = detect_mmode_wave((const unsigned char*)mask, lane);

    __shared__ short res[LSEQ];
    __shared__ int st[TB_STK];             // packed (i<<16)|j
    for (int l = lane; l < LSEQ; l += 64) res[l] = -1;
    st[0] = (0 << 16) | (LSEQ - 1);        // all lanes, same addr, same value
    __syncthreads();

    int sp = 1;                            // uniform across lanes
    for (int iter = 0; iter < 4096 && sp > 0; ++iter) {
        --sp;
        int pk = st[sp];
        int i = pk >> 16, j = pk & 0xFFFF;
        if (i >= j) continue;
        int c = choice_read(mask, mb + (size_t)j * LSEQ + i, mmode);

        if (c == 0) {
            st[sp] = ((i + 1) << 16) | j; ++sp;
        } else if (c == 1) {
            st[sp] = (i << 16) | (j - 1); ++sp;
        } else if (c == 2) {
            res[i] = (short)j; res[j] = (short)i;
            if (i + 1 <= j - 1) { st[sp] = ((i + 1) << 16) | (j - 1); ++sp; }
        } else {
            const int d = j - i;
            const float* rowi = dp + (size_t)i * LSEQ;
            const float* mrow = dp + (size_t)j * LSEQ;
            float bv = BIGV; int bt = d;   // sentinel t for lex-min
            for (int t = lane; t < d; t += 64) {
                float cc = rowi[i + t] + mrow[i + t];
                if (cc < bv || (cc == bv && t < bt)) { bv = cc; bt = t; }
            }
            for (int m = 32; m > 0; m >>= 1) {
                float ov = __shfl_xor(bv, m, 64);
                int   ot = __shfl_xor(bt, m, 64);
                if (ov < bv || (ov == bv && ot < bt)) { bv = ov; bt = ot; }
            }
            int k = i + bt;
            if (sp < TB_STK - 2) {
                st[sp] = (i << 16) | k; ++sp;            // (i,k) below
                st[sp] = ((k + 1) << 16) | j; ++sp;      // (k+1,j) popped first
            }
        }
        __syncthreads();                   // order LDS writes before next pop
    }

    for (int l = lane; l < LSEQ; l += 64)
        out[b * LSEQ + l] = (float)res[l];               // pairs FIRST, f32
    if (lane == 0)
        out[BATCH * LSEQ + b] = dp[LSEQ - 1];            // energy = dp[0][L-1]
}

extern "C" void kernel_launch(void* const* d_in, const int* in_sizes, int n_in,
                              void* d_out, int out_size, void* d_ws, size_t ws_size,
                              hipStream_t stream) {
    float* e_pair = (float*)d_in[0];        // consumed & overwritten in-place by dp
    const float* e_unp = (const float*)d_in[1];
    void* mask = d_in[2];                   // upper tri read; lower tri = choice store
    (void)d_ws; (void)ws_size;              // zero workspace

    dp_kernel<<<BATCH, 1024, 0, stream>>>(e_pair, e_unp, mask);
    tb_kernel<<<BATCH, 64, 0, stream>>>(e_pair, mask, (float*)d_out);
}